// Round 1
// baseline (2634.593 us; speedup 1.0000x reference)
//
#include <hip/hip_runtime.h>

// ---------------------------------------------------------------------------
// GraphAllEdgeNet on MI355X.
// Pipeline:
//   0) histogram of active-edge counts per dst for mask m1/m2  -> inv counts
//   1) compact active edge lists (unsorted; atomic cursors)
//   2) stage0: per-node 512->64 fp32 tiled GEMM (+bias, BN, ReLU) -> bf16 feats
//   3) audio/video heads from gf
//   4) 4 blocks x 2 edge passes: MFMA edge-message kernel (K=128 fused
//      [d-part | xi-part] GEMM -> BN/ReLU -> K=64 GEMM), fp32 atomic
//      aggregation into acc; finalize kernel does mean + residual + BN/ReLU
//   5) final 64->2 head
// Layout facts used (measured, from the guide):
//   mfma_f32_16x16x32_bf16: A[m=lane&15][k=(lane>>4)*8+j],
//                           B[k=(lane>>4)*8+j][n=lane&15],
//                           C/D: col=lane&15, row=(lane>>4)*4+reg.
// ---------------------------------------------------------------------------

#define NN 100000
#define NE 800000
#define BNS 0.9999950000374998f  // 1/sqrt(1+1e-5)

typedef __attribute__((ext_vector_type(8))) short short8;
typedef __attribute__((ext_vector_type(4))) float f32x4;

__device__ __forceinline__ float bf_lo(unsigned u){ union{unsigned i; float f;} v; v.i = u << 16; return v.f; }
__device__ __forceinline__ float bf_hi(unsigned u){ union{unsigned i; float f;} v; v.i = u & 0xffff0000u; return v.f; }
__device__ __forceinline__ float bf2f(unsigned short u){ union{unsigned i; float f;} v; v.i = ((unsigned)u) << 16; return v.f; }
__device__ __forceinline__ unsigned short f2bf(float f){
  union{float f; unsigned i;} v; v.f = f;
  unsigned r = v.i + 0x7fffu + ((v.i >> 16) & 1u);   // RNE
  return (unsigned short)(r >> 16);
}
__device__ __forceinline__ unsigned packbf(float a, float b){
  return (unsigned)f2bf(a) | ((unsigned)f2bf(b) << 16);
}

// ---------------- preprocessing -------------------------------------------

__global__ __launch_bounds__(256) void hist_kernel(
    const int* __restrict__ ei, const int* __restrict__ edel,
    const int* __restrict__ esel, int* cnt1, int* cnt2)
{
  int e = blockIdx.x * 256 + threadIdx.x;
  if (e >= NE) return;
  int d = edel[e], s = esel[e], dst = ei[NE + e];
  if (d < 1) atomicAdd(cnt1 + dst, 1);
  if ((d >= 1 && d < 4) || s == 1) atomicAdd(cnt2 + dst, 1);
}

__global__ __launch_bounds__(256) void inv_kernel(
    const int* __restrict__ cnt1, const int* __restrict__ cnt2,
    float* inv1, float* inv2)
{
  int i = blockIdx.x * 256 + threadIdx.x;
  if (i >= NN) return;
  inv1[i] = 1.f / fmaxf((float)cnt1[i], 1.f);
  inv2[i] = 1.f / fmaxf((float)cnt2[i], 1.f);
}

__global__ __launch_bounds__(256) void compact_kernel(
    const int* __restrict__ ei, const int* __restrict__ edel,
    const int* __restrict__ esel, int* ctr,
    int* s1s, int* s1d, int* s2s, int* s2d)
{
  int e = blockIdx.x * 256 + threadIdx.x;
  if (e >= NE) return;
  int d = edel[e], s = esel[e], src = ei[e], dst = ei[NE + e];
  if (d < 1){ int p = atomicAdd(ctr + 0, 1); s1s[p] = src; s1d[p] = dst; }
  if ((d >= 1 && d < 4) || s == 1){ int p = atomicAdd(ctr + 1, 1); s2s[p] = src; s2d[p] = dst; }
}

// ---------------- stage 0: node projection --------------------------------
// grid.x = 782 (64 nodes/type/block), grid.y = type (0 audio/even, 1 video/odd)

__global__ __launch_bounds__(256) void s0_kernel(
    const float* __restrict__ x,
    const float* __restrict__ W0a, const float* __restrict__ b0a,
    const float* __restrict__ W0v, const float* __restrict__ b0v,
    const float* __restrict__ bn0g, const float* __restrict__ bn0b,
    unsigned short* __restrict__ Xb)
{
  const int t = blockIdx.y;
  const float* __restrict__ W    = t ? W0v : W0a;
  const float* __restrict__ bias = t ? b0v : b0a;
  const int m0 = blockIdx.x * 64;
  const int tid = threadIdx.x;
  const int ty = tid >> 4, tx = tid & 15;

  __shared__ float As[16][68];  // [k][node], pad 68: <=2-way on scalar writes
  __shared__ float Bs[16][72];  // [k][chan], pad 72: dense-uniform f4 writes

  float accu[4][4] = {{0.f}};

  const int lr = tid >> 2, lq = tid & 3;
  int node = m0 + lr; if (node > 49999) node = 49999;
  const float* xp = x + (2 * node + t) * 1024 + t * 512 + lq * 4;
  const int bk = tid >> 4, bc = tid & 15;
  const float* wp = W + bk * 64 + bc * 4;

  for (int k0 = 0; k0 < 512; k0 += 16){
    float4 av = *(const float4*)(xp + k0);
    float4 bv = *(const float4*)(wp + k0 * 64);
    __syncthreads();
    As[lq*4+0][lr] = av.x;
    As[lq*4+1][lr] = av.y;
    As[lq*4+2][lr] = av.z;
    As[lq*4+3][lr] = av.w;
    *(float4*)(&Bs[bk][bc*4]) = bv;
    __syncthreads();
#pragma unroll
    for (int kk = 0; kk < 16; kk++){
      float4 a = *(const float4*)(&As[kk][ty*4]);
      float4 b = *(const float4*)(&Bs[kk][tx*4]);
      accu[0][0] = fmaf(a.x,b.x,accu[0][0]); accu[0][1] = fmaf(a.x,b.y,accu[0][1]);
      accu[0][2] = fmaf(a.x,b.z,accu[0][2]); accu[0][3] = fmaf(a.x,b.w,accu[0][3]);
      accu[1][0] = fmaf(a.y,b.x,accu[1][0]); accu[1][1] = fmaf(a.y,b.y,accu[1][1]);
      accu[1][2] = fmaf(a.y,b.z,accu[1][2]); accu[1][3] = fmaf(a.y,b.w,accu[1][3]);
      accu[2][0] = fmaf(a.z,b.x,accu[2][0]); accu[2][1] = fmaf(a.z,b.y,accu[2][1]);
      accu[2][2] = fmaf(a.z,b.z,accu[2][2]); accu[2][3] = fmaf(a.z,b.w,accu[2][3]);
      accu[3][0] = fmaf(a.w,b.x,accu[3][0]); accu[3][1] = fmaf(a.w,b.y,accu[3][1]);
      accu[3][2] = fmaf(a.w,b.z,accu[3][2]); accu[3][3] = fmaf(a.w,b.w,accu[3][3]);
    }
  }

#pragma unroll
  for (int rr = 0; rr < 4; rr++){
    int nd = m0 + ty * 4 + rr;
    if (nd < 50000){
      int i = 2 * nd + t;
      float v[4];
#pragma unroll
      for (int cc = 0; cc < 4; cc++){
        int c = tx * 4 + cc;
        float u = accu[rr][cc] + bias[c];
        v[cc] = fmaxf(fmaf(u, BNS * bn0g[c], bn0b[c]), 0.f);
      }
      uint2 w; w.x = packbf(v[0], v[1]); w.y = packbf(v[2], v[3]);
      *(uint2*)(Xb + i * 64 + tx * 4) = w;
    }
  }
}

// ---------------- edge-message MFMA kernel --------------------------------
// One wave handles 16-edge chunks (grid-stride). Transposed GEMMs:
//   D1[c'][e] = sum_k W1cat[k][c'] * rcat[e][k]   (K=128, 16 mfma)
//   D2[c2][e] = sum_c W2[c][c2]    * r2[e][c]     (K=64,   8 mfma)
// rcat = [relu(bn1b(f_src - f_dst)) | relu(bn1a(f_dst))]
// W1cat rows: k<64 -> W1[64+k] (d-part), k>=64 -> W1[k-64] (xi-part)

__global__ __launch_bounds__(256) void edge_pass(
    const unsigned short* __restrict__ fin,
    const int* __restrict__ ssrc, const int* __restrict__ sdst,
    const int* __restrict__ Sp,
    const float* __restrict__ W1, const float* __restrict__ W2,
    const float* __restrict__ bn1g, const float* __restrict__ bn1b,
    const float* __restrict__ bn2g, const float* __restrict__ bn2b,
    float* __restrict__ acc, int nwaves)
{
  const int l   = threadIdx.x & 63;
  const int wv  = threadIdx.x >> 6;
  const int q   = l >> 4;
  const int m16 = l & 15;
  const int ge  = l >> 2;          // gather: edge within chunk
  const int gc0 = (l & 3) << 4;    // gather: channel window base

  __shared__ unsigned short r_lds[4][16 * 136];   // [edge][128 + 8 pad] bf16
  __shared__ unsigned short r2_lds[4][16 * 72];   // [edge][64 + 8 pad]  bf16
  unsigned short* rt  = &r_lds[wv][0];
  unsigned short* r2t = &r2_lds[wv][0];

  // A-operand fragments (weights, transposed) resident in VGPRs
  short8 a1[4][4], a2[4][2];
#pragma unroll
  for (int t = 0; t < 4; t++){
#pragma unroll
    for (int h = 0; h < 4; h++){
      short8 v;
#pragma unroll
      for (int j = 0; j < 8; j++){
        int kg = h * 32 + q * 8 + j;
        int cp = t * 16 + m16;
        float w = (kg < 64) ? W1[(64 + kg) * 64 + cp] : W1[(kg - 64) * 64 + cp];
        v[j] = (short)f2bf(w);
      }
      a1[t][h] = v;
    }
#pragma unroll
    for (int h = 0; h < 2; h++){
      short8 v;
#pragma unroll
      for (int j = 0; j < 8; j++){
        int kg = h * 32 + q * 8 + j;
        v[j] = (short)f2bf(W2[kg * 64 + t * 16 + m16]);
      }
      a2[t][h] = v;
    }
  }

  float s1a[16], t1a[16], s1b[16], t1b[16];
#pragma unroll
  for (int j = 0; j < 16; j++){
    s1a[j] = BNS * bn1g[gc0 + j];       t1a[j] = bn1b[gc0 + j];
    s1b[j] = BNS * bn1g[64 + gc0 + j];  t1b[j] = bn1b[64 + gc0 + j];
  }
  f32x4 s2v[4], t2v[4];
#pragma unroll
  for (int t = 0; t < 4; t++){
#pragma unroll
    for (int r = 0; r < 4; r++){
      s2v[t][r] = BNS * bn2g[t * 16 + q * 4 + r];
      t2v[t][r] = bn2b[t * 16 + q * 4 + r];
    }
  }

  const int S = *Sp;
  const int nch = (S + 15) >> 4;
  const int wgid = (blockIdx.x << 2) + wv;

  for (int ch = wgid; ch < nch; ch += nwaves){
    // ---- gather + elementwise -> rcat tile in LDS
    int eg = ch * 16 + ge; if (eg > S - 1) eg = S - 1;
    int src = ssrc[eg];
    int dsn = sdst[eg];
    const uint4* ps = (const uint4*)(fin + src * 64 + gc0);
    const uint4* pd = (const uint4*)(fin + dsn * 64 + gc0);
    uint4 su0 = ps[0], su1 = ps[1];
    uint4 du0 = pd[0], du1 = pd[1];

    unsigned sa[8] = {su0.x,su0.y,su0.z,su0.w,su1.x,su1.y,su1.z,su1.w};
    unsigned da[8] = {du0.x,du0.y,du0.z,du0.w,du1.x,du1.y,du1.z,du1.w};
    unsigned rb[8], ra[8];
#pragma unroll
    for (int p = 0; p < 8; p++){
      float fd0 = bf_lo(da[p]), fd1 = bf_hi(da[p]);
      float d0 = bf_lo(sa[p]) - fd0, d1 = bf_hi(sa[p]) - fd1;
      float rb0 = fmaxf(fmaf(d0,  s1b[2*p],   t1b[2*p]),   0.f);
      float rb1 = fmaxf(fmaf(d1,  s1b[2*p+1], t1b[2*p+1]), 0.f);
      float ra0 = fmaxf(fmaf(fd0, s1a[2*p],   t1a[2*p]),   0.f);
      float ra1 = fmaxf(fmaf(fd1, s1a[2*p+1], t1a[2*p+1]), 0.f);
      rb[p] = packbf(rb0, rb1);
      ra[p] = packbf(ra0, ra1);
    }
    unsigned short* wr = rt + ge * 136 + gc0;
    { uint4 u; u.x=rb[0]; u.y=rb[1]; u.z=rb[2]; u.w=rb[3]; *(uint4*)(wr)      = u; }
    { uint4 u; u.x=rb[4]; u.y=rb[5]; u.z=rb[6]; u.w=rb[7]; *(uint4*)(wr + 8)  = u; }
    { uint4 u; u.x=ra[0]; u.y=ra[1]; u.z=ra[2]; u.w=ra[3]; *(uint4*)(wr + 64) = u; }
    { uint4 u; u.x=ra[4]; u.y=ra[5]; u.z=ra[6]; u.w=ra[7]; *(uint4*)(wr + 72) = u; }

    __builtin_amdgcn_wave_barrier();   // wave-synchronous LDS: order writes->reads

    // ---- GEMM1 (K=128) + bn2/relu -> r2 tile
    const unsigned short* rrow = rt + m16 * 136 + q * 8;
    short8 b1[4];
#pragma unroll
    for (int h = 0; h < 4; h++) b1[h] = *(const short8*)(rrow + h * 32);

#pragma unroll
    for (int t = 0; t < 4; t++){
      f32x4 c = {0.f, 0.f, 0.f, 0.f};
      c = __builtin_amdgcn_mfma_f32_16x16x32_bf16(a1[t][0], b1[0], c, 0, 0, 0);
      c = __builtin_amdgcn_mfma_f32_16x16x32_bf16(a1[t][1], b1[1], c, 0, 0, 0);
      c = __builtin_amdgcn_mfma_f32_16x16x32_bf16(a1[t][2], b1[2], c, 0, 0, 0);
      c = __builtin_amdgcn_mfma_f32_16x16x32_bf16(a1[t][3], b1[3], c, 0, 0, 0);
      unsigned p0 = packbf(fmaxf(c[0]*s2v[t][0]+t2v[t][0], 0.f),
                           fmaxf(c[1]*s2v[t][1]+t2v[t][1], 0.f));
      unsigned p1 = packbf(fmaxf(c[2]*s2v[t][2]+t2v[t][2], 0.f),
                           fmaxf(c[3]*s2v[t][3]+t2v[t][3], 0.f));
      uint2 w; w.x = p0; w.y = p1;
      *(uint2*)(r2t + m16 * 72 + t * 16 + q * 4) = w;
    }

    __builtin_amdgcn_wave_barrier();

    // ---- GEMM2 (K=64) + masked atomic aggregation
    const unsigned short* r2row = r2t + m16 * 72 + q * 8;
    short8 b2[2];
    b2[0] = *(const short8*)(r2row);
    b2[1] = *(const short8*)(r2row + 32);

    int ee = ch * 16 + m16;
    int ecl = ee > S - 1 ? S - 1 : ee;
    int dstl = sdst[ecl];
    bool valid = ee < S;
    float* ap = acc + dstl * 64 + q * 4;
#pragma unroll
    for (int t = 0; t < 4; t++){
      f32x4 c = {0.f, 0.f, 0.f, 0.f};
      c = __builtin_amdgcn_mfma_f32_16x16x32_bf16(a2[t][0], b2[0], c, 0, 0, 0);
      c = __builtin_amdgcn_mfma_f32_16x16x32_bf16(a2[t][1], b2[1], c, 0, 0, 0);
      if (valid){
        atomicAdd(ap + t * 16 + 0, c[0]);
        atomicAdd(ap + t * 16 + 1, c[1]);
        atomicAdd(ap + t * 16 + 2, c[2]);
        atomicAdd(ap + t * 16 + 3, c[3]);
      }
    }
    __builtin_amdgcn_wave_barrier();   // protect LDS reuse across chunks
  }
}

// ---------------- finalize: mean + residual + BN/ReLU + re-zero acc -------

__global__ __launch_bounds__(256) void finalize_kernel(
    float* acc, const float* __restrict__ inv,
    const unsigned short* resid,       // no __restrict__: may alias outb
    const float* __restrict__ bng, const float* __restrict__ bnb,
    unsigned short* outb, int hasres, int hasbn)
{
  int idx = blockIdx.x * 256 + threadIdx.x;   // exactly NN*16 threads
  int i = idx >> 4, c4 = (idx & 15) << 2;
  float4 a = *(float4*)(acc + idx * 4);
  float iv = inv[i];
  float v0 = a.x * iv, v1 = a.y * iv, v2 = a.z * iv, v3 = a.w * iv;
  if (hasres){
    uint2 r = *(const uint2*)(resid + idx * 4);
    v0 += bf_lo(r.x); v1 += bf_hi(r.x); v2 += bf_lo(r.y); v3 += bf_hi(r.y);
  }
  if (hasbn){
    v0 = fmaxf(fmaf(v0, BNS * bng[c4+0], bnb[c4+0]), 0.f);
    v1 = fmaxf(fmaf(v1, BNS * bng[c4+1], bnb[c4+1]), 0.f);
    v2 = fmaxf(fmaf(v2, BNS * bng[c4+2], bnb[c4+2]), 0.f);
    v3 = fmaxf(fmaf(v3, BNS * bng[c4+3], bnb[c4+3]), 0.f);
  }
  uint2 w; w.x = packbf(v0, v1); w.y = packbf(v2, v3);
  *(uint2*)(outb + idx * 4) = w;
  *(float4*)(acc + idx * 4) = make_float4(0.f, 0.f, 0.f, 0.f);
}

// ---------------- heads ----------------------------------------------------

__global__ __launch_bounds__(256) void head_final(
    const unsigned short* __restrict__ Xb,
    const float* __restrict__ Wf, const float* __restrict__ bf,
    float* __restrict__ out)
{
  int i = (blockIdx.x << 2) + (threadIdx.x >> 6);
  if (i >= NN) return;
  int l = threadIdx.x & 63;
  float v = bf2f(Xb[i * 64 + l]);
  float2 w = *(const float2*)(Wf + l * 2);
  float p0 = v * w.x, p1 = v * w.y;
#pragma unroll
  for (int off = 32; off; off >>= 1){
    p0 += __shfl_xor(p0, off);
    p1 += __shfl_xor(p1, off);
  }
  if (l == 0){ out[i * 2] = p0 + bf[0]; out[i * 2 + 1] = p1 + bf[1]; }
}

__global__ __launch_bounds__(256) void head_av(
    const unsigned short* __restrict__ Xb,
    const float* __restrict__ Wa, const float* __restrict__ ba,
    const float* __restrict__ Wv, const float* __restrict__ bv,
    float* __restrict__ outA, float* __restrict__ outV)
{
  int i = (blockIdx.x << 2) + (threadIdx.x >> 6);
  if (i >= NN) return;
  int l = threadIdx.x & 63;
  const float* Wf = (i & 1) ? Wv : Wa;
  const float* bb = (i & 1) ? bv : ba;
  float* o = (i & 1) ? (outV + (i >> 1) * 2) : (outA + (i >> 1) * 2);
  float v = bf2f(Xb[i * 64 + l]);
  float2 w = *(const float2*)(Wf + l * 2);
  float p0 = v * w.x, p1 = v * w.y;
#pragma unroll
  for (int off = 32; off; off >>= 1){
    p0 += __shfl_xor(p0, off);
    p1 += __shfl_xor(p1, off);
  }
  if (l == 0){ o[0] = p0 + bb[0]; o[1] = p1 + bb[1]; }
}

// ---------------- launcher -------------------------------------------------

extern "C" void kernel_launch(void* const* d_in, const int* in_sizes, int n_in,
                              void* d_out, int out_size, void* d_ws, size_t ws_size,
                              hipStream_t stream)
{
  const float* x    = (const float*)d_in[0];
  const int*   ei   = (const int*)d_in[1];
  const int*   edel = (const int*)d_in[2];
  const int*   esel = (const int*)d_in[3];
  // d_in[4] audio_node_mask: structurally (i%2==0); parity used directly.
  const float* W0a  = (const float*)d_in[5];
  const float* b0a  = (const float*)d_in[6];
  const float* W0v  = (const float*)d_in[7];
  const float* b0v  = (const float*)d_in[8];
  const float* bn0g = (const float*)d_in[9];
  const float* bn0b = (const float*)d_in[10];
  const float* ec1g = (const float*)d_in[11];
  const float* ec1b = (const float*)d_in[12];
  const float* ecW1 = (const float*)d_in[13];
  const float* ec2g = (const float*)d_in[14];
  const float* ec2b = (const float*)d_in[15];
  const float* ecW2 = (const float*)d_in[16];
  const float* bng  = (const float*)d_in[17];
  const float* bnb  = (const float*)d_in[18];
  const float* fcaW = (const float*)d_in[19];
  const float* fcab = (const float*)d_in[20];
  const float* fcvW = (const float*)d_in[21];
  const float* fcvb = (const float*)d_in[22];
  const float* fcW  = (const float*)d_in[23];
  const float* fcb  = (const float*)d_in[24];
  float* out = (float*)d_out;

  char* ws = (char*)d_ws;
  float*          acc  = (float*)(ws + 0);                    // 25,600,000 B
  int*            cnt1 = (int*)(ws + 25600000);               //    400,000
  int*            cnt2 = (int*)(ws + 26000000);               //    400,000
  int*            ctr  = (int*)(ws + 26400000);               //        256
  float*          inv1 = (float*)(ws + 26400256);             //    400,000
  float*          inv2 = (float*)(ws + 26800256);             //    400,000
  unsigned short* Xb   = (unsigned short*)(ws + 27200256);    // 12,800,000
  unsigned short* Yb   = (unsigned short*)(ws + 40000256);    // 12,800,000
  int*            s1s  = (int*)(ws + 52800256);               //  3,200,000
  int*            s1d  = (int*)(ws + 56000256);
  int*            s2s  = (int*)(ws + 59200256);
  int*            s2d  = (int*)(ws + 62400256);               // end 65,600,256

  // zero acc | cnt1 | cnt2 | ctr (contiguous)
  hipMemsetAsync(ws, 0, 26400256, stream);

  hist_kernel<<<(NE + 255) / 256, 256, 0, stream>>>(ei, edel, esel, cnt1, cnt2);
  inv_kernel<<<(NN + 255) / 256, 256, 0, stream>>>(cnt1, cnt2, inv1, inv2);
  compact_kernel<<<(NE + 255) / 256, 256, 0, stream>>>(ei, edel, esel, ctr, s1s, s1d, s2s, s2d);

  dim3 g0(782, 2, 1);
  s0_kernel<<<g0, 256, 0, stream>>>(x, W0a, b0a, W0v, b0v, bn0g, bn0b, Xb);
  head_av<<<25000, 256, 0, stream>>>(Xb, fcaW, fcab, fcvW, fcvb,
                                     out + 2 * NN, out + 2 * NN + 100000);

  const int EB = 512;
  const int nwaves = EB * 4;
  const int FG = (NN * 16) / 256;   // 6250

  for (int k = 0; k < 4; k++){
    const float* W1  = ecW1 + k * 128 * 64;
    const float* W2  = ecW2 + k * 64 * 64;
    const float* g1p = ec1g + k * 128;
    const float* b1p = ec1b + k * 128;
    const float* g2p = ec2g + k * 64;
    const float* b2p = ec2b + k * 64;

    edge_pass<<<EB, 256, 0, stream>>>(Xb, s1s, s1d, ctr + 0,
                                      W1, W2, g1p, b1p, g2p, b2p, acc, nwaves);
    finalize_kernel<<<FG, 256, 0, stream>>>(acc, inv1, nullptr, nullptr, nullptr,
                                            Yb, 0, 0);
    edge_pass<<<EB, 256, 0, stream>>>(Yb, s2s, s2d, ctr + 1,
                                      W1, W2, g1p, b1p, g2p, b2p, acc, nwaves);
    const unsigned short* resid = (k == 0) ? nullptr : Xb;
    const float* bg = (k < 3) ? (bng + k * 64) : nullptr;
    const float* bb = (k < 3) ? (bnb + k * 64) : nullptr;
    finalize_kernel<<<FG, 256, 0, stream>>>(acc, inv2, resid, bg, bb,
                                            Xb, (k == 0) ? 0 : 1, (k < 3) ? 1 : 0);
  }

  head_final<<<25000, 256, 0, stream>>>(Xb, fcW, fcb, out);
}

// Round 2
// 1029.767 us; speedup vs baseline: 2.5584x; 2.5584x over previous
//
#include <hip/hip_runtime.h>

// ---------------------------------------------------------------------------
// GraphAllEdgeNet on MI355X — round 2: atomic-free aggregation.
//   preproc: hist -> exclusive scan (CSR row) -> dst-sorted compaction
//   stage0 : per-node 512->64 fp32 GEMM (+bias,BN,ReLU) -> bf16 feats
//   passes : msg_pass (MFMA K=128 fused [d|xi] GEMM -> BN/ReLU -> K=64 GEMM,
//            bf16 msg store) ; aggregate (CSR segmented mean + residual +
//            BN/ReLU fused, one wave per dst)
// MFMA layout (measured): mfma_f32_16x16x32_bf16
//   A[m=lane&15][k=(lane>>4)*8+j], B[k=(lane>>4)*8+j][n=lane&15],
//   C/D: col=lane&15, row=(lane>>4)*4+reg.
// ---------------------------------------------------------------------------

#define NN 100000
#define NE 800000
#define NB 391                 // ceil(NN/256)
#define BNS 0.9999950000374998f

typedef __attribute__((ext_vector_type(8))) short short8;
typedef __attribute__((ext_vector_type(4))) float f32x4;

__device__ __forceinline__ float bf_lo(unsigned u){ union{unsigned i; float f;} v; v.i = u << 16; return v.f; }
__device__ __forceinline__ float bf_hi(unsigned u){ union{unsigned i; float f;} v; v.i = u & 0xffff0000u; return v.f; }
__device__ __forceinline__ float bf2f(unsigned short u){ union{unsigned i; float f;} v; v.i = ((unsigned)u) << 16; return v.f; }
__device__ __forceinline__ unsigned short f2bf(float f){
  union{float f; unsigned i;} v; v.f = f;
  unsigned r = v.i + 0x7fffu + ((v.i >> 16) & 1u);   // RNE
  return (unsigned short)(r >> 16);
}
__device__ __forceinline__ unsigned packbf(float a, float b){
  return (unsigned)f2bf(a) | ((unsigned)f2bf(b) << 16);
}

// ---------------- preprocessing -------------------------------------------

__global__ __launch_bounds__(256) void hist_kernel(
    const int* __restrict__ ei, const int* __restrict__ edel,
    const int* __restrict__ esel, int* cnt1, int* cnt2)
{
  int e = blockIdx.x * 256 + threadIdx.x;
  if (e >= NE) return;
  int d = edel[e], s = esel[e], dst = ei[NE + e];
  if (d < 1) atomicAdd(cnt1 + dst, 1);
  if ((d >= 1 && d < 4) || s == 1) atomicAdd(cnt2 + dst, 1);
}

// block-local exclusive scan of cnt -> row ; block totals -> bsum
__global__ __launch_bounds__(256) void scan1_kernel(
    const int* __restrict__ cnt1, const int* __restrict__ cnt2,
    int* row1, int* row2, int* bsum)
{
  const int a = blockIdx.y;
  const int* cnt = a ? cnt2 : cnt1;
  int* row = a ? row2 : row1;
  int t = threadIdx.x, b = blockIdx.x, i = b * 256 + t;
  int v = (i < NN) ? cnt[i] : 0;
  __shared__ int sc[256];
  sc[t] = v; __syncthreads();
#pragma unroll
  for (int off = 1; off < 256; off <<= 1){
    int x = (t >= off) ? sc[t - off] : 0;
    __syncthreads();
    sc[t] += x;
    __syncthreads();
  }
  if (i < NN) row[i] = sc[t] - v;
  if (t == 255) bsum[a * 400 + b] = sc[t];
}

// scan the 391 block totals for both arrays; totals -> ctr[0..1]
__global__ __launch_bounds__(512) void scan2_kernel(int* bsum, int* boff, int* ctr)
{
  int t = threadIdx.x;
  __shared__ int sc[512];
  for (int a = 0; a < 2; a++){
    int v = (t < NB) ? bsum[a * 400 + t] : 0;
    __syncthreads();
    sc[t] = v; __syncthreads();
#pragma unroll
    for (int off = 1; off < 512; off <<= 1){
      int x = (t >= off) ? sc[t - off] : 0;
      __syncthreads();
      sc[t] += x;
      __syncthreads();
    }
    if (t < NB) boff[a * 400 + t] = sc[t] - v;
    if (t == NB - 1) ctr[a] = sc[t];
  }
}

__global__ __launch_bounds__(256) void scan3_kernel(
    int* row1, int* row2, int* cur1, int* cur2, const int* __restrict__ boff)
{
  const int a = blockIdx.y;
  int* row = a ? row2 : row1;
  int* cur = a ? cur2 : cur1;
  int i = blockIdx.x * 256 + threadIdx.x;
  if (i >= NN) return;
  int r = row[i] + boff[a * 400 + blockIdx.x];
  row[i] = r;
  cur[i] = r;
}

__global__ __launch_bounds__(256) void inv_kernel(
    const int* __restrict__ cnt1, const int* __restrict__ cnt2,
    float* inv1, float* inv2)
{
  int i = blockIdx.x * 256 + threadIdx.x;
  if (i >= NN) return;
  inv1[i] = 1.f / fmaxf((float)cnt1[i], 1.f);
  inv2[i] = 1.f / fmaxf((float)cnt2[i], 1.f);
}

__global__ __launch_bounds__(256) void compact_kernel(
    const int* __restrict__ ei, const int* __restrict__ edel,
    const int* __restrict__ esel, int* cur1, int* cur2,
    int* s1s, int* s1d, int* s2s, int* s2d)
{
  int e = blockIdx.x * 256 + threadIdx.x;
  if (e >= NE) return;
  int d = edel[e], s = esel[e], src = ei[e], dst = ei[NE + e];
  if (d < 1){ int p = atomicAdd(cur1 + dst, 1); s1s[p] = src; s1d[p] = dst; }
  if ((d >= 1 && d < 4) || s == 1){ int p = atomicAdd(cur2 + dst, 1); s2s[p] = src; s2d[p] = dst; }
}

// pre-convert W1cat / W2 into MFMA A-fragment-layout bf16
// wf1: [k][frag f=t*4+h][lane][8], wf2: [k][frag f=t*2+h][lane][8]
__global__ __launch_bounds__(256) void prep_w(
    const float* __restrict__ W1, const float* __restrict__ W2,
    unsigned short* __restrict__ wf1, unsigned short* __restrict__ wf2)
{
  int g = blockIdx.x * 256 + threadIdx.x;
  if (g >= 6144) return;
  int k = g / 1536, r = g % 1536, f = r >> 6, l = r & 63;
  int q = l >> 4, m = l & 15;
  if (f < 16){
    int t = f >> 2, h = f & 3;
    unsigned short* o = wf1 + (((size_t)k * 16 + f) * 64 + l) * 8;
    const float* Wk = W1 + k * 8192;
#pragma unroll
    for (int j = 0; j < 8; j++){
      int kg = h * 32 + q * 8 + j;
      int cp = t * 16 + m;
      float w = (kg < 64) ? Wk[(64 + kg) * 64 + cp] : Wk[(kg - 64) * 64 + cp];
      o[j] = f2bf(w);
    }
  } else {
    int f2 = f - 16, t = f2 >> 1, h = f2 & 1;
    unsigned short* o = wf2 + (((size_t)k * 8 + f2) * 64 + l) * 8;
    const float* Wk = W2 + k * 4096;
#pragma unroll
    for (int j = 0; j < 8; j++){
      int kg = h * 32 + q * 8 + j;
      o[j] = f2bf(Wk[kg * 64 + t * 16 + m]);
    }
  }
}

// ---------------- stage 0: node projection --------------------------------

__global__ __launch_bounds__(256) void s0_kernel(
    const float* __restrict__ x,
    const float* __restrict__ W0a, const float* __restrict__ b0a,
    const float* __restrict__ W0v, const float* __restrict__ b0v,
    const float* __restrict__ bn0g, const float* __restrict__ bn0b,
    unsigned short* __restrict__ Xb)
{
  const int t = blockIdx.y;
  const float* __restrict__ W    = t ? W0v : W0a;
  const float* __restrict__ bias = t ? b0v : b0a;
  const int m0 = blockIdx.x * 64;
  const int tid = threadIdx.x;
  const int ty = tid >> 4, tx = tid & 15;

  __shared__ float As[16][68];
  __shared__ float Bs[16][72];

  float accu[4][4] = {{0.f}};

  const int lr = tid >> 2, lq = tid & 3;
  int node = m0 + lr; if (node > 49999) node = 49999;
  const float* xp = x + (2 * node + t) * 1024 + t * 512 + lq * 4;
  const int bk = tid >> 4, bc = tid & 15;
  const float* wp = W + bk * 64 + bc * 4;

  for (int k0 = 0; k0 < 512; k0 += 16){
    float4 av = *(const float4*)(xp + k0);
    float4 bv = *(const float4*)(wp + k0 * 64);
    __syncthreads();
    As[lq*4+0][lr] = av.x;
    As[lq*4+1][lr] = av.y;
    As[lq*4+2][lr] = av.z;
    As[lq*4+3][lr] = av.w;
    *(float4*)(&Bs[bk][bc*4]) = bv;
    __syncthreads();
#pragma unroll
    for (int kk = 0; kk < 16; kk++){
      float4 a = *(const float4*)(&As[kk][ty*4]);
      float4 b = *(const float4*)(&Bs[kk][tx*4]);
      accu[0][0] = fmaf(a.x,b.x,accu[0][0]); accu[0][1] = fmaf(a.x,b.y,accu[0][1]);
      accu[0][2] = fmaf(a.x,b.z,accu[0][2]); accu[0][3] = fmaf(a.x,b.w,accu[0][3]);
      accu[1][0] = fmaf(a.y,b.x,accu[1][0]); accu[1][1] = fmaf(a.y,b.y,accu[1][1]);
      accu[1][2] = fmaf(a.y,b.z,accu[1][2]); accu[1][3] = fmaf(a.y,b.w,accu[1][3]);
      accu[2][0] = fmaf(a.z,b.x,accu[2][0]); accu[2][1] = fmaf(a.z,b.y,accu[2][1]);
      accu[2][2] = fmaf(a.z,b.z,accu[2][2]); accu[2][3] = fmaf(a.z,b.w,accu[2][3]);
      accu[3][0] = fmaf(a.w,b.x,accu[3][0]); accu[3][1] = fmaf(a.w,b.y,accu[3][1]);
      accu[3][2] = fmaf(a.w,b.z,accu[3][2]); accu[3][3] = fmaf(a.w,b.w,accu[3][3]);
    }
  }

#pragma unroll
  for (int rr = 0; rr < 4; rr++){
    int nd = m0 + ty * 4 + rr;
    if (nd < 50000){
      int i = 2 * nd + t;
      float v[4];
#pragma unroll
      for (int cc = 0; cc < 4; cc++){
        int c = tx * 4 + cc;
        float u = accu[rr][cc] + bias[c];
        v[cc] = fmaxf(fmaf(u, BNS * bn0g[c], bn0b[c]), 0.f);
      }
      uint2 w; w.x = packbf(v[0], v[1]); w.y = packbf(v[2], v[3]);
      *(uint2*)(Xb + i * 64 + tx * 4) = w;
    }
  }
}

// ---------------- Phase A: edge-message MFMA kernel -----------------------
// One wave per 16-edge chunk (grid-stride); writes bf16 msg rows (no atomics).

__global__ __launch_bounds__(256) void msg_pass(
    const unsigned short* __restrict__ fin,
    const int* __restrict__ ssrc, const int* __restrict__ sdst,
    const int* __restrict__ Sp,
    const unsigned short* __restrict__ wf1, const unsigned short* __restrict__ wf2,
    const float* __restrict__ bn1g, const float* __restrict__ bn1b,
    const float* __restrict__ bn2g, const float* __restrict__ bn2b,
    unsigned short* __restrict__ msg, int nwaves)
{
  const int l   = threadIdx.x & 63;
  const int wv  = threadIdx.x >> 6;
  const int q   = l >> 4;
  const int m16 = l & 15;
  const int ge  = l >> 2;          // gather: edge within chunk
  const int gc0 = (l & 3) << 4;    // gather: channel window base

  __shared__ unsigned short r_lds[4][16 * 136];   // [edge][128 + 8 pad] bf16
  __shared__ unsigned short r2_lds[4][16 * 72];   // [edge][64 + 8 pad]  bf16
  unsigned short* rt  = &r_lds[wv][0];
  unsigned short* r2t = &r2_lds[wv][0];

  // A-operand weight fragments: pre-laid-out bf16, one 16B load each
  short8 a1[4][4], a2[4][2];
#pragma unroll
  for (int t = 0; t < 4; t++){
#pragma unroll
    for (int h = 0; h < 4; h++)
      a1[t][h] = *(const short8*)(wf1 + (((size_t)(t * 4 + h)) * 64 + l) * 8);
#pragma unroll
    for (int h = 0; h < 2; h++)
      a2[t][h] = *(const short8*)(wf2 + (((size_t)(t * 2 + h)) * 64 + l) * 8);
  }

  float s1a[16], t1a[16], s1b[16], t1b[16];
#pragma unroll
  for (int j = 0; j < 16; j++){
    s1a[j] = BNS * bn1g[gc0 + j];       t1a[j] = bn1b[gc0 + j];
    s1b[j] = BNS * bn1g[64 + gc0 + j];  t1b[j] = bn1b[64 + gc0 + j];
  }
  f32x4 s2v[4], t2v[4];
#pragma unroll
  for (int t = 0; t < 4; t++){
#pragma unroll
    for (int r = 0; r < 4; r++){
      s2v[t][r] = BNS * bn2g[t * 16 + q * 4 + r];
      t2v[t][r] = bn2b[t * 16 + q * 4 + r];
    }
  }

  const int S = *Sp;
  const int nch = (S + 15) >> 4;
  const int wgid = (blockIdx.x << 2) + wv;

  for (int ch = wgid; ch < nch; ch += nwaves){
    // ---- gather + BN1/ReLU elementwise -> rcat tile in LDS
    int eg = ch * 16 + ge; if (eg > S - 1) eg = S - 1;
    int src = ssrc[eg];
    int dsn = sdst[eg];
    const uint4* ps = (const uint4*)(fin + src * 64 + gc0);
    const uint4* pd = (const uint4*)(fin + dsn * 64 + gc0);
    uint4 su0 = ps[0], su1 = ps[1];
    uint4 du0 = pd[0], du1 = pd[1];

    unsigned sa[8] = {su0.x,su0.y,su0.z,su0.w,su1.x,su1.y,su1.z,su1.w};
    unsigned da[8] = {du0.x,du0.y,du0.z,du0.w,du1.x,du1.y,du1.z,du1.w};
    unsigned rb[8], ra[8];
#pragma unroll
    for (int p = 0; p < 8; p++){
      float fd0 = bf_lo(da[p]), fd1 = bf_hi(da[p]);
      float d0 = bf_lo(sa[p]) - fd0, d1 = bf_hi(sa[p]) - fd1;
      float rb0 = fmaxf(fmaf(d0,  s1b[2*p],   t1b[2*p]),   0.f);
      float rb1 = fmaxf(fmaf(d1,  s1b[2*p+1], t1b[2*p+1]), 0.f);
      float ra0 = fmaxf(fmaf(fd0, s1a[2*p],   t1a[2*p]),   0.f);
      float ra1 = fmaxf(fmaf(fd1, s1a[2*p+1], t1a[2*p+1]), 0.f);
      rb[p] = packbf(rb0, rb1);
      ra[p] = packbf(ra0, ra1);
    }
    unsigned short* wr = rt + ge * 136 + gc0;
    { uint4 u; u.x=rb[0]; u.y=rb[1]; u.z=rb[2]; u.w=rb[3]; *(uint4*)(wr)      = u; }
    { uint4 u; u.x=rb[4]; u.y=rb[5]; u.z=rb[6]; u.w=rb[7]; *(uint4*)(wr + 8)  = u; }
    { uint4 u; u.x=ra[0]; u.y=ra[1]; u.z=ra[2]; u.w=ra[3]; *(uint4*)(wr + 64) = u; }
    { uint4 u; u.x=ra[4]; u.y=ra[5]; u.z=ra[6]; u.w=ra[7]; *(uint4*)(wr + 72) = u; }

    __builtin_amdgcn_wave_barrier();   // wave-synchronous LDS ordering

    // ---- GEMM1 (K=128) + BN2/ReLU -> r2 tile
    const unsigned short* rrow = rt + m16 * 136 + q * 8;
    short8 b1[4];
#pragma unroll
    for (int h = 0; h < 4; h++) b1[h] = *(const short8*)(rrow + h * 32);

#pragma unroll
    for (int t = 0; t < 4; t++){
      f32x4 c = {0.f, 0.f, 0.f, 0.f};
      c = __builtin_amdgcn_mfma_f32_16x16x32_bf16(a1[t][0], b1[0], c, 0, 0, 0);
      c = __builtin_amdgcn_mfma_f32_16x16x32_bf16(a1[t][1], b1[1], c, 0, 0, 0);
      c = __builtin_amdgcn_mfma_f32_16x16x32_bf16(a1[t][2], b1[2], c, 0, 0, 0);
      c = __builtin_amdgcn_mfma_f32_16x16x32_bf16(a1[t][3], b1[3], c, 0, 0, 0);
      unsigned p0 = packbf(fmaxf(c[0]*s2v[t][0]+t2v[t][0], 0.f),
                           fmaxf(c[1]*s2v[t][1]+t2v[t][1], 0.f));
      unsigned p1 = packbf(fmaxf(c[2]*s2v[t][2]+t2v[t][2], 0.f),
                           fmaxf(c[3]*s2v[t][3]+t2v[t][3], 0.f));
      uint2 w; w.x = p0; w.y = p1;
      *(uint2*)(r2t + m16 * 72 + t * 16 + q * 4) = w;
    }

    __builtin_amdgcn_wave_barrier();

    // ---- GEMM2 (K=64) -> bf16 msg store
    const unsigned short* r2row = r2t + m16 * 72 + q * 8;
    short8 b2[2];
    b2[0] = *(const short8*)(r2row);
    b2[1] = *(const short8*)(r2row + 32);

    int ee = ch * 16 + m16;
    bool valid = ee < S;
    unsigned short* mp = msg + (size_t)ee * 64 + (q << 2);
#pragma unroll
    for (int t = 0; t < 4; t++){
      f32x4 c = {0.f, 0.f, 0.f, 0.f};
      c = __builtin_amdgcn_mfma_f32_16x16x32_bf16(a2[t][0], b2[0], c, 0, 0, 0);
      c = __builtin_amdgcn_mfma_f32_16x16x32_bf16(a2[t][1], b2[1], c, 0, 0, 0);
      if (valid){
        uint2 w; w.x = packbf(c[0], c[1]); w.y = packbf(c[2], c[3]);
        *(uint2*)(mp + t * 16) = w;
      }
    }
    __builtin_amdgcn_wave_barrier();   // protect LDS reuse across chunks
  }
}

// ---------------- Phase B: CSR segmented mean + residual + BN/ReLU --------
// One wave per dst node; lane = channel.

__global__ __launch_bounds__(256) void aggregate_kernel(
    const unsigned short* __restrict__ msg,
    const int* __restrict__ row, const int* __restrict__ cnt,
    const float* __restrict__ inv,
    const unsigned short* resid,           // may alias outb (same-index RMW)
    const float* __restrict__ bng, const float* __restrict__ bnb,
    unsigned short* outb, int hasres, int hasbn)
{
  int d = (blockIdx.x << 2) + (threadIdx.x >> 6);
  if (d >= NN) return;
  int l = threadIdx.x & 63;
  int r0 = row[d], deg = cnt[d];
  const unsigned short* mp = msg + (size_t)r0 * 64 + l;
  float s0 = 0.f, s1 = 0.f;
  int j = 0;
  for (; j + 1 < deg; j += 2){
    s0 += bf2f(mp[(size_t)j * 64]);
    s1 += bf2f(mp[(size_t)(j + 1) * 64]);
  }
  if (j < deg) s0 += bf2f(mp[(size_t)j * 64]);
  float v = (s0 + s1) * inv[d];
  if (hasres) v += bf2f(resid[d * 64 + l]);
  if (hasbn)  v = fmaxf(fmaf(v, BNS * bng[l], bnb[l]), 0.f);
  outb[d * 64 + l] = f2bf(v);
}

// ---------------- heads ----------------------------------------------------

__global__ __launch_bounds__(256) void head_final(
    const unsigned short* __restrict__ Xb,
    const float* __restrict__ Wf, const float* __restrict__ bf,
    float* __restrict__ out)
{
  int i = (blockIdx.x << 2) + (threadIdx.x >> 6);
  if (i >= NN) return;
  int l = threadIdx.x & 63;
  float v = bf2f(Xb[i * 64 + l]);
  float2 w = *(const float2*)(Wf + l * 2);
  float p0 = v * w.x, p1 = v * w.y;
#pragma unroll
  for (int off = 32; off; off >>= 1){
    p0 += __shfl_xor(p0, off);
    p1 += __shfl_xor(p1, off);
  }
  if (l == 0){ out[i * 2] = p0 + bf[0]; out[i * 2 + 1] = p1 + bf[1]; }
}

__global__ __launch_bounds__(256) void head_av(
    const unsigned short* __restrict__ Xb,
    const float* __restrict__ Wa, const float* __restrict__ ba,
    const float* __restrict__ Wv, const float* __restrict__ bv,
    float* __restrict__ outA, float* __restrict__ outV)
{
  int i = (blockIdx.x << 2) + (threadIdx.x >> 6);
  if (i >= NN) return;
  int l = threadIdx.x & 63;
  const float* Wf = (i & 1) ? Wv : Wa;
  const float* bb = (i & 1) ? bv : ba;
  float* o = (i & 1) ? (outV + (i >> 1) * 2) : (outA + (i >> 1) * 2);
  float v = bf2f(Xb[i * 64 + l]);
  float2 w = *(const float2*)(Wf + l * 2);
  float p0 = v * w.x, p1 = v * w.y;
#pragma unroll
  for (int off = 32; off; off >>= 1){
    p0 += __shfl_xor(p0, off);
    p1 += __shfl_xor(p1, off);
  }
  if (l == 0){ o[0] = p0 + bb[0]; o[1] = p1 + bb[1]; }
}

// ---------------- launcher -------------------------------------------------

extern "C" void kernel_launch(void* const* d_in, const int* in_sizes, int n_in,
                              void* d_out, int out_size, void* d_ws, size_t ws_size,
                              hipStream_t stream)
{
  const float* x    = (const float*)d_in[0];
  const int*   ei   = (const int*)d_in[1];
  const int*   edel = (const int*)d_in[2];
  const int*   esel = (const int*)d_in[3];
  // d_in[4] audio_node_mask: structurally (i%2==0); parity used directly.
  const float* W0a  = (const float*)d_in[5];
  const float* b0a  = (const float*)d_in[6];
  const float* W0v  = (const float*)d_in[7];
  const float* b0v  = (const float*)d_in[8];
  const float* bn0g = (const float*)d_in[9];
  const float* bn0b = (const float*)d_in[10];
  const float* ec1g = (const float*)d_in[11];
  const float* ec1b = (const float*)d_in[12];
  const float* ecW1 = (const float*)d_in[13];
  const float* ec2g = (const float*)d_in[14];
  const float* ec2b = (const float*)d_in[15];
  const float* ecW2 = (const float*)d_in[16];
  const float* bng  = (const float*)d_in[17];
  const float* bnb  = (const float*)d_in[18];
  const float* fcaW = (const float*)d_in[19];
  const float* fcab = (const float*)d_in[20];
  const float* fcvW = (const float*)d_in[21];
  const float* fcvb = (const float*)d_in[22];
  const float* fcW  = (const float*)d_in[23];
  const float* fcb  = (const float*)d_in[24];
  float* out = (float*)d_out;

  char* ws = (char*)d_ws;
  unsigned short* msg  = (unsigned short*)(ws + 0);            // 102,400,000
  unsigned short* Xb   = (unsigned short*)(ws + 102400000);    //  12,800,000
  unsigned short* Yb   = (unsigned short*)(ws + 115200000);    //  12,800,000
  int*            s1s  = (int*)(ws + 128000000);               //   3,200,000
  int*            s1d  = (int*)(ws + 131200000);
  int*            s2s  = (int*)(ws + 134400000);
  int*            s2d  = (int*)(ws + 137600000);
  int*            cnt1 = (int*)(ws + 140800000);               //     400,000
  int*            cnt2 = (int*)(ws + 141200000);
  int*            row1 = (int*)(ws + 141600000);
  int*            row2 = (int*)(ws + 142000000);
  int*            cur1 = (int*)(ws + 142400000);
  int*            cur2 = (int*)(ws + 142800000);
  float*          inv1 = (float*)(ws + 143200000);
  float*          inv2 = (float*)(ws + 143600000);
  int*            bsum = (int*)(ws + 144000000);               //       3,200
  int*            boff = (int*)(ws + 144003200);               //       3,200
  int*            ctr  = (int*)(ws + 144006400);               //          64
  unsigned short* wf1  = (unsigned short*)(ws + 144006464);    //      65,536
  unsigned short* wf2  = (unsigned short*)(ws + 144072000);    //      32,768
  // total: 144,104,768 bytes

  // zero only the histogram counters
  hipMemsetAsync(cnt1, 0, 800000, stream);

  hist_kernel<<<(NE + 255) / 256, 256, 0, stream>>>(ei, edel, esel, cnt1, cnt2);
  scan1_kernel<<<dim3(NB, 2), 256, 0, stream>>>(cnt1, cnt2, row1, row2, bsum);
  scan2_kernel<<<1, 512, 0, stream>>>(bsum, boff, ctr);
  scan3_kernel<<<dim3(NB, 2), 256, 0, stream>>>(row1, row2, cur1, cur2, boff);
  inv_kernel<<<NB, 256, 0, stream>>>(cnt1, cnt2, inv1, inv2);
  compact_kernel<<<(NE + 255) / 256, 256, 0, stream>>>(ei, edel, esel, cur1, cur2,
                                                       s1s, s1d, s2s, s2d);
  prep_w<<<24, 256, 0, stream>>>(ecW1, ecW2, wf1, wf2);

  dim3 g0(782, 2, 1);
  s0_kernel<<<g0, 256, 0, stream>>>(x, W0a, b0a, W0v, b0v, bn0g, bn0b, Xb);
  head_av<<<25000, 256, 0, stream>>>(Xb, fcaW, fcab, fcvW, fcvb,
                                     out + 2 * NN, out + 2 * NN + 100000);

  const int EB = 1024;          // 4 waves/block; ~all resident at 4 blocks/CU
  const int nwaves = EB * 4;

  for (int k = 0; k < 4; k++){
    const unsigned short* w1k = wf1 + (size_t)k * 16 * 64 * 8;
    const unsigned short* w2k = wf2 + (size_t)k * 8 * 64 * 8;
    const float* g1p = ec1g + k * 128;
    const float* b1p = ec1b + k * 128;
    const float* g2p = ec2g + k * 64;
    const float* b2p = ec2b + k * 64;

    msg_pass<<<EB, 256, 0, stream>>>(Xb, s1s, s1d, ctr + 0, w1k, w2k,
                                     g1p, b1p, g2p, b2p, msg, nwaves);
    aggregate_kernel<<<25000, 256, 0, stream>>>(msg, row1, cnt1, inv1,
                                                nullptr, nullptr, nullptr,
                                                Yb, 0, 0);
    msg_pass<<<EB, 256, 0, stream>>>(Yb, s2s, s2d, ctr + 1, w1k, w2k,
                                     g1p, b1p, g2p, b2p, msg, nwaves);
    const unsigned short* resid = (k == 0) ? nullptr : Xb;
    const float* bg = (k < 3) ? (bng + k * 64) : nullptr;
    const float* bb = (k < 3) ? (bnb + k * 64) : nullptr;
    aggregate_kernel<<<25000, 256, 0, stream>>>(msg, row2, cnt2, inv2,
                                                resid, bg, bb,
                                                Xb, (k == 0) ? 0 : 1, (k < 3) ? 1 : 0);
  }

  head_final<<<25000, 256, 0, stream>>>(Xb, fcW, fcb, out);
}